// Round 1
// baseline (682.002 us; speedup 1.0000x reference)
//
#include <hip/hip_runtime.h>

// NeuralTransformationCache: multi-res hash grid encode + 3-layer MLP.
// Inputs (d_in order): xyz[N,3] f32, bmin[3], bmax[3], table[L=16,T=32768,F=4] f32,
//                      w0[64,64], w1[64,64], w2[64,8] f32.
// Output d_out (concat, f32): mask[N], d_xyz[N,3], d_rot[N,4]  -> 8N floats.

#define LVL 16
#define TSZ 32768
#define PR1 2654435761u
#define PR2 805459861u

__global__ __launch_bounds__(256) void ntc_kernel(
    const float* __restrict__ xyz,
    const float* __restrict__ bmin,
    const float* __restrict__ bmax,
    const float* __restrict__ table,
    const float* __restrict__ w0,
    const float* __restrict__ w1,
    const float* __restrict__ w2,
    float* __restrict__ out, int N)
{
    const int i = blockIdx.x * 256 + threadIdx.x;
    if (i >= N) return;

    const float bx0 = bmin[0], by0 = bmin[1], bz0 = bmin[2];
    const float ex = bmax[0] - bx0, ey = bmax[1] - by0, ez = bmax[2] - bz0;

    const float cx = (xyz[3*i + 0] - bx0) / ex;
    const float cy = (xyz[3*i + 1] - by0) / ey;
    const float cz = (xyz[3*i + 2] - bz0) / ez;

    const bool inside = (cx >= 0.f) && (cx <= 1.f) &&
                        (cy >= 0.f) && (cy <= 1.f) &&
                        (cz >= 0.f) && (cz <= 1.f);

    const float x = fminf(fmaxf(cx, 0.f), 1.f);
    const float y = fminf(fmaxf(cy, 0.f), 1.f);
    const float z = fminf(fmaxf(cz, 0.f), 1.f);

    // ---- layer-0 accumulators (encode is fused into the first GEMV) ----
    float h0[64];
#pragma unroll
    for (int j = 0; j < 64; ++j) h0[j] = 0.f;

    const float4* __restrict__ tab = reinterpret_cast<const float4*>(table);

    for (int l = 0; l < LVL; ++l) {
        const float scale = 16.f * (float)(1u << l);   // exact in f32
        const float px = x * scale, py = y * scale, pz = z * scale;
        const float fx = floorf(px), fy = floorf(py), fz = floorf(pz);
        const float rx = px - fx, ry = py - fy, rz = pz - fz;
        const unsigned ux = (unsigned)fx, uy = (unsigned)fy, uz = (unsigned)fz;

        const unsigned hx[2] = { ux,        ux + 1u };
        const unsigned hy[2] = { uy * PR1, (uy + 1u) * PR1 };  // uint32 wraparound
        const unsigned hz[2] = { uz * PR2, (uz + 1u) * PR2 };
        const float    wx[2] = { 1.f - rx, rx };
        const float    wy[2] = { 1.f - ry, ry };
        const float    wz[2] = { 1.f - rz, rz };

        float a0 = 0.f, a1 = 0.f, a2 = 0.f, a3 = 0.f;
#pragma unroll
        for (int c = 0; c < 8; ++c) {
            const int ox = (c >> 2) & 1, oy = (c >> 1) & 1, oz = c & 1;
            const unsigned idx = (hx[ox] ^ hy[oy] ^ hz[oz]) & (TSZ - 1u);
            const float4 f4 = tab[l * TSZ + idx];
            const float w = wx[ox] * wy[oy] * wz[oz];
            a0 = fmaf(w, f4.x, a0);
            a1 = fmaf(w, f4.y, a1);
            a2 = fmaf(w, f4.z, a2);
            a3 = fmaf(w, f4.w, a3);
        }

        const float e0[4] = { a0, a1, a2, a3 };
#pragma unroll
        for (int f = 0; f < 4; ++f) {
            const float* __restrict__ wr = w0 + (l * 4 + f) * 64;  // wave-uniform row
            const float ef = e0[f];
#pragma unroll
            for (int j = 0; j < 64; ++j) h0[j] = fmaf(ef, wr[j], h0[j]);
        }
    }

    // ---- relu + layer 1 ----
#pragma unroll
    for (int j = 0; j < 64; ++j) h0[j] = fmaxf(h0[j], 0.f);

    float h1[64];
#pragma unroll
    for (int j = 0; j < 64; ++j) h1[j] = 0.f;

    for (int k = 0; k < 64; ++k) {
        const float* __restrict__ wr = w1 + k * 64;   // wave-uniform row
        const float e = h0[k];
#pragma unroll
        for (int j = 0; j < 64; ++j) h1[j] = fmaf(e, wr[j], h1[j]);
    }

#pragma unroll
    for (int j = 0; j < 64; ++j) h1[j] = fmaxf(h1[j], 0.f);

    // ---- layer 2 (64 -> 8) ----
    float r[8];
#pragma unroll
    for (int j = 0; j < 8; ++j) r[j] = 0.f;

    for (int k = 0; k < 64; ++k) {
        const float* __restrict__ wr = w2 + k * 8;    // wave-uniform row
        const float e = h1[k];
#pragma unroll
        for (int j = 0; j < 8; ++j) r[j] = fmaf(e, wr[j], r[j]);
    }

    // ---- masked writes: mask[N] | d_xyz[N,3] | d_rot[N,4] ----
    out[i] = inside ? 1.f : 0.f;

    float* __restrict__ dxyz = out + N;
    dxyz[3*i + 0] = inside ? r[0] : 0.f;
    dxyz[3*i + 1] = inside ? r[1] : 0.f;
    dxyz[3*i + 2] = inside ? r[2] : 0.f;

    float4* __restrict__ drot = reinterpret_cast<float4*>(out + 4 * (size_t)N);
    drot[i] = inside ? make_float4(r[3], r[4], r[5], r[6])
                     : make_float4(1.f, 0.f, 0.f, 0.f);
}

extern "C" void kernel_launch(void* const* d_in, const int* in_sizes, int n_in,
                              void* d_out, int out_size, void* d_ws, size_t ws_size,
                              hipStream_t stream) {
    const float* xyz   = (const float*)d_in[0];
    const float* bmin  = (const float*)d_in[1];
    const float* bmax  = (const float*)d_in[2];
    const float* table = (const float*)d_in[3];
    const float* w0    = (const float*)d_in[4];
    const float* w1    = (const float*)d_in[5];
    const float* w2    = (const float*)d_in[6];
    float* out = (float*)d_out;

    const int N = in_sizes[0] / 3;
    const int blocks = (N + 255) / 256;
    ntc_kernel<<<blocks, 256, 0, stream>>>(xyz, bmin, bmax, table, w0, w1, w2, out, N);
}

// Round 2
// 615.823 us; speedup vs baseline: 1.1075x; 1.1075x over previous
//
#include <hip/hip_runtime.h>
#include <hip/hip_bf16.h>

// NeuralTransformationCache: hash-grid encode (f32, per-thread) + bf16 MFMA MLP.
// Block = 256 threads = 4 waves; each wave owns 64 points, block owns 256.
// LDS: encT[8][256][8] bf16 (32KB, doubles as f32 res[256][8] at the end),
//      w0t/w1t [n][k] bf16 (8KB each), w2t [16][64] bf16 (2KB). Total 50KB -> 3 blocks/CU.

#define LVL 16
#define TSZ 32768
#define PR1 2654435761u
#define PR2 805459861u

typedef __attribute__((ext_vector_type(8))) short bf16x8;
typedef __attribute__((ext_vector_type(4))) float f32x4;
typedef __attribute__((ext_vector_type(4))) unsigned short u16x4;

__device__ __forceinline__ unsigned short f2bf(float f) {
    return __builtin_bit_cast(unsigned short, __float2bfloat16(f));
}

__global__ __launch_bounds__(256) void ntc_kernel(
    const float* __restrict__ xyz,
    const float* __restrict__ bmin,
    const float* __restrict__ bmax,
    const float* __restrict__ table,
    const float* __restrict__ w0,
    const float* __restrict__ w1,
    const float* __restrict__ w2,
    float* __restrict__ out, int N)
{
    // encT element index: kt*2048 + pt*8 + j   (kt 0..7 = k>>3, pt 0..255 block-local, j = k&7)
    __shared__ unsigned short encT[8 * 256 * 8];   // 32KB
    __shared__ unsigned short w0t[64 * 64];        // [n][k]
    __shared__ unsigned short w1t[64 * 64];
    __shared__ unsigned short w2t[16 * 64];        // n 8..15 zero-padded

    const int t  = threadIdx.x;
    const int wv = t >> 6;        // wave 0..3
    const int ln = t & 63;        // lane
    const int col = ln & 15;      // M-row / N-col within 16x16 tile
    const int g   = ln >> 4;      // k-group (0..3)

    // ---- stage weights: transposed [n][k], bf16 (coalesced global reads) ----
#pragma unroll
    for (int it = 0; it < 16; ++it) {
        const int idx = it * 256 + t;         // = k*64 + n
        const int k = idx >> 6, n = idx & 63;
        w0t[n * 64 + k] = f2bf(w0[idx]);
        w1t[n * 64 + k] = f2bf(w1[idx]);
    }
#pragma unroll
    for (int q = 0; q < 4; ++q) {
        const int idx = t * 4 + q;            // w2t linear = n*64 + k
        const int n = idx >> 6, k = idx & 63;
        w2t[idx] = (n < 8) ? f2bf(w2[k * 8 + n]) : (unsigned short)0;
    }

    // ---- encode (f32, per-thread) -> encT bf16 ----
    const int i  = blockIdx.x * 256 + t;
    const int ic = (i < N) ? i : (N - 1);

    const float bx0 = bmin[0], by0 = bmin[1], bz0 = bmin[2];
    const float ex = bmax[0] - bx0, ey = bmax[1] - by0, ez = bmax[2] - bz0;

    const float cx = (xyz[3 * ic + 0] - bx0) / ex;
    const float cy = (xyz[3 * ic + 1] - by0) / ey;
    const float cz = (xyz[3 * ic + 2] - bz0) / ez;

    const bool inside = (cx >= 0.f) && (cx <= 1.f) &&
                        (cy >= 0.f) && (cy <= 1.f) &&
                        (cz >= 0.f) && (cz <= 1.f);

    const float x = fminf(fmaxf(cx, 0.f), 1.f);
    const float y = fminf(fmaxf(cy, 0.f), 1.f);
    const float z = fminf(fmaxf(cz, 0.f), 1.f);

    const float4* __restrict__ tab = reinterpret_cast<const float4*>(table);

    for (int l = 0; l < LVL; ++l) {
        const float scale = 16.f * (float)(1u << l);
        const float px = x * scale, py = y * scale, pz = z * scale;
        const float fx = floorf(px), fy = floorf(py), fz = floorf(pz);
        const float rx = px - fx, ry = py - fy, rz = pz - fz;
        const unsigned ux = (unsigned)fx, uy = (unsigned)fy, uz = (unsigned)fz;

        const unsigned hx[2] = { ux,        ux + 1u };
        const unsigned hy[2] = { uy * PR1, (uy + 1u) * PR1 };
        const unsigned hz[2] = { uz * PR2, (uz + 1u) * PR2 };
        const float    wx[2] = { 1.f - rx, rx };
        const float    wy[2] = { 1.f - ry, ry };
        const float    wz[2] = { 1.f - rz, rz };

        float a0 = 0.f, a1 = 0.f, a2 = 0.f, a3 = 0.f;
#pragma unroll
        for (int c = 0; c < 8; ++c) {
            const int ox = (c >> 2) & 1, oy = (c >> 1) & 1, oz = c & 1;
            const unsigned idx = (hx[ox] ^ hy[oy] ^ hz[oz]) & (TSZ - 1u);
            const float4 f4 = tab[l * TSZ + idx];
            const float w = wx[ox] * wy[oy] * wz[oz];
            a0 = fmaf(w, f4.x, a0);
            a1 = fmaf(w, f4.y, a1);
            a2 = fmaf(w, f4.z, a2);
            a3 = fmaf(w, f4.w, a3);
        }
        // features 4l..4l+3 -> k-tile l>>1, j offset (l&1)*4
        u16x4 v = { f2bf(a0), f2bf(a1), f2bf(a2), f2bf(a3) };
        *reinterpret_cast<u16x4*>(&encT[(l >> 1) * 2048 + t * 8 + (l & 1) * 4]) = v;
    }

    __syncthreads();

    // ---- layer 0: H = relu(ENC @ W0), per-wave 64x64 ----
    // A-frag (16x16x32): lane holds A[row = ln&15][k = kk*32 + g*8 + e]
    // B-frag:            lane holds B[k = kk*32 + g*8 + e][col = ln&15]
    // D:                 lane reg r = D[row = g*4 + r][col = ln&15]
    f32x4 acc[4][4];
#pragma unroll
    for (int mt = 0; mt < 4; ++mt)
#pragma unroll
        for (int nt = 0; nt < 4; ++nt) acc[mt][nt] = (f32x4){0.f, 0.f, 0.f, 0.f};

#pragma unroll
    for (int kk = 0; kk < 2; ++kk) {
        bf16x8 a[4];
#pragma unroll
        for (int mt = 0; mt < 4; ++mt)
            a[mt] = *reinterpret_cast<bf16x8*>(
                &encT[(kk * 4 + g) * 2048 + (wv * 64 + mt * 16 + col) * 8]);
#pragma unroll
        for (int nt = 0; nt < 4; ++nt) {
            bf16x8 b = *reinterpret_cast<bf16x8*>(
                &w0t[(nt * 16 + col) * 64 + kk * 32 + g * 8]);
#pragma unroll
            for (int mt = 0; mt < 4; ++mt)
                acc[mt][nt] = __builtin_amdgcn_mfma_f32_16x16x32_bf16(a[mt], b, acc[mt][nt], 0, 0, 0);
        }
    }

    __syncthreads();
    // relu + write H back to encT (bf16), wave-private region
#pragma unroll
    for (int mt = 0; mt < 4; ++mt)
#pragma unroll
        for (int nt = 0; nt < 4; ++nt) {
            const int kt = nt * 2 + (col >> 3), j = col & 7;
#pragma unroll
            for (int r = 0; r < 4; ++r) {
                const float h = fmaxf(acc[mt][nt][r], 0.f);
                encT[kt * 2048 + (wv * 64 + mt * 16 + g * 4 + r) * 8 + j] = f2bf(h);
            }
        }
    __syncthreads();

    // ---- layer 1 ----
#pragma unroll
    for (int mt = 0; mt < 4; ++mt)
#pragma unroll
        for (int nt = 0; nt < 4; ++nt) acc[mt][nt] = (f32x4){0.f, 0.f, 0.f, 0.f};

#pragma unroll
    for (int kk = 0; kk < 2; ++kk) {
        bf16x8 a[4];
#pragma unroll
        for (int mt = 0; mt < 4; ++mt)
            a[mt] = *reinterpret_cast<bf16x8*>(
                &encT[(kk * 4 + g) * 2048 + (wv * 64 + mt * 16 + col) * 8]);
#pragma unroll
        for (int nt = 0; nt < 4; ++nt) {
            bf16x8 b = *reinterpret_cast<bf16x8*>(
                &w1t[(nt * 16 + col) * 64 + kk * 32 + g * 8]);
#pragma unroll
            for (int mt = 0; mt < 4; ++mt)
                acc[mt][nt] = __builtin_amdgcn_mfma_f32_16x16x32_bf16(a[mt], b, acc[mt][nt], 0, 0, 0);
        }
    }

    __syncthreads();
#pragma unroll
    for (int mt = 0; mt < 4; ++mt)
#pragma unroll
        for (int nt = 0; nt < 4; ++nt) {
            const int kt = nt * 2 + (col >> 3), j = col & 7;
#pragma unroll
            for (int r = 0; r < 4; ++r) {
                const float h = fmaxf(acc[mt][nt][r], 0.f);
                encT[kt * 2048 + (wv * 64 + mt * 16 + g * 4 + r) * 8 + j] = f2bf(h);
            }
        }
    __syncthreads();

    // ---- layer 2: RES = H1 @ W2 (N padded to 16) ----
    f32x4 acc2[4];
#pragma unroll
    for (int mt = 0; mt < 4; ++mt) acc2[mt] = (f32x4){0.f, 0.f, 0.f, 0.f};

#pragma unroll
    for (int kk = 0; kk < 2; ++kk) {
        bf16x8 a[4];
#pragma unroll
        for (int mt = 0; mt < 4; ++mt)
            a[mt] = *reinterpret_cast<bf16x8*>(
                &encT[(kk * 4 + g) * 2048 + (wv * 64 + mt * 16 + col) * 8]);
        bf16x8 b = *reinterpret_cast<bf16x8*>(&w2t[col * 64 + kk * 32 + g * 8]);
#pragma unroll
        for (int mt = 0; mt < 4; ++mt)
            acc2[mt] = __builtin_amdgcn_mfma_f32_16x16x32_bf16(a[mt], b, acc2[mt], 0, 0, 0);
    }

    __syncthreads();
    // stage results to LDS (f32, overlaps encT) then per-thread masked writes
    float* res = reinterpret_cast<float*>(encT);   // res[pt][8], 8KB
    if (col < 8) {
#pragma unroll
        for (int mt = 0; mt < 4; ++mt)
#pragma unroll
            for (int r = 0; r < 4; ++r)
                res[(wv * 64 + mt * 16 + g * 4 + r) * 8 + col] = acc2[mt][r];
    }
    __syncthreads();

    if (i < N) {
        const f32x4 lo = *reinterpret_cast<f32x4*>(&res[t * 8 + 0]);
        const f32x4 hi = *reinterpret_cast<f32x4*>(&res[t * 8 + 4]);

        out[i] = inside ? 1.f : 0.f;

        float* __restrict__ dxyz = out + N;
        dxyz[3 * i + 0] = inside ? lo.x : 0.f;
        dxyz[3 * i + 1] = inside ? lo.y : 0.f;
        dxyz[3 * i + 2] = inside ? lo.z : 0.f;

        float4* __restrict__ drot = reinterpret_cast<float4*>(out + 4 * (size_t)N);
        drot[i] = inside ? make_float4(lo.w, hi.x, hi.y, hi.z)
                         : make_float4(1.f, 0.f, 0.f, 0.f);
    }
}

extern "C" void kernel_launch(void* const* d_in, const int* in_sizes, int n_in,
                              void* d_out, int out_size, void* d_ws, size_t ws_size,
                              hipStream_t stream) {
    const float* xyz   = (const float*)d_in[0];
    const float* bmin  = (const float*)d_in[1];
    const float* bmax  = (const float*)d_in[2];
    const float* table = (const float*)d_in[3];
    const float* w0    = (const float*)d_in[4];
    const float* w1    = (const float*)d_in[5];
    const float* w2    = (const float*)d_in[6];
    float* out = (float*)d_out;

    const int N = in_sizes[0] / 3;
    const int blocks = (N + 255) / 256;
    ntc_kernel<<<blocks, 256, 0, stream>>>(xyz, bmin, bmax, table, w0, w1, w2, out, N);
}

// Round 3
// 512.155 us; speedup vs baseline: 1.3316x; 1.2024x over previous
//
#include <hip/hip_runtime.h>
#include <hip/hip_bf16.h>

// NeuralTransformationCache, 3-phase: K0 table/weight prep -> K1 encode -> K2 MFMA MLP.
// Fallback to fused single kernel if ws_size is too small.

#define LVL 16
#define TSZ 32768
#define PR1 2654435761u
#define PR2 805459861u

typedef __attribute__((ext_vector_type(8))) short bf16x8;
typedef __attribute__((ext_vector_type(4))) float f32x4;
typedef __attribute__((ext_vector_type(4))) unsigned short u16x4;

__device__ __forceinline__ unsigned short f2bf(float f) {
    return __builtin_bit_cast(unsigned short, __float2bfloat16(f));
}

// ---------------- K0a: table f32 -> bf16 ----------------
__global__ __launch_bounds__(256) void k_tbl(const float* __restrict__ t,
                                             unsigned short* __restrict__ o, int n8) {
    const int g = blockIdx.x * 256 + threadIdx.x;
    if (g >= n8) return;
    const float4* tf = reinterpret_cast<const float4*>(t);
    const float4 a = tf[g * 2], b = tf[g * 2 + 1];
    bf16x8 v;
    v[0] = (short)f2bf(a.x); v[1] = (short)f2bf(a.y);
    v[2] = (short)f2bf(a.z); v[3] = (short)f2bf(a.w);
    v[4] = (short)f2bf(b.x); v[5] = (short)f2bf(b.y);
    v[6] = (short)f2bf(b.z); v[7] = (short)f2bf(b.w);
    *reinterpret_cast<bf16x8*>(o + (size_t)g * 8) = v;
}

// ---------------- K0b: weights -> MFMA-fragment order, bf16 ----------------
// wf layout (shorts): wf0[4096] | wf1[4096] | wf2[1024]
// frag index: (((nt*2+kk)*64 + lane)*8 + e) holds B[k = kk*32 + (lane>>4)*8 + e][n = nt*16 + (lane&15)]
__global__ void k_wts(const float* __restrict__ w0, const float* __restrict__ w1,
                      const float* __restrict__ w2, unsigned short* __restrict__ wf) {
    const int t = threadIdx.x;
#pragma unroll
    for (int q = 0; q < 16; ++q) {
        const int s = q * 256 + t;
        const int e = s & 7, f = s >> 3;
        const int lnn = f & 63, ntkk = f >> 6;
        const int k = (ntkk & 1) * 32 + (lnn >> 4) * 8 + e;
        const int n = (ntkk >> 1) * 16 + (lnn & 15);
        wf[s]        = f2bf(w0[k * 64 + n]);
        wf[4096 + s] = f2bf(w1[k * 64 + n]);
    }
#pragma unroll
    for (int q = 0; q < 4; ++q) {
        const int s = q * 256 + t;
        const int e = s & 7, f = s >> 3;
        const int lnn = f & 63, kk = f >> 6;
        const int k = kk * 32 + (lnn >> 4) * 8 + e;
        const int n = lnn & 15;
        wf[8192 + s] = (n < 8) ? f2bf(w2[k * 8 + n]) : (unsigned short)0;
    }
}

// ---------------- K1: encode (latency-optimized, no LDS, no barriers) ----------------
// enc layout: chunk-major, region c (c=0..7 = feature bytes [c*16, c*16+16)) at enc + c*Npad*8 shorts,
// pt row = 8 shorts. Chunk c holds levels 2c (shorts 0..3) and 2c+1 (shorts 4..7).
__global__ __launch_bounds__(256) void k_enc(
    const float* __restrict__ xyz, const float* __restrict__ bmin, const float* __restrict__ bmax,
    const unsigned short* __restrict__ tbl, float* __restrict__ out,
    unsigned short* __restrict__ enc, int N, int Npad)
{
    const int i = blockIdx.x * 256 + threadIdx.x;
    if (i >= N) return;

    const float bx0 = bmin[0], by0 = bmin[1], bz0 = bmin[2];
    const float ex = bmax[0] - bx0, ey = bmax[1] - by0, ez = bmax[2] - bz0;

    const float cx = (xyz[3 * i + 0] - bx0) / ex;
    const float cy = (xyz[3 * i + 1] - by0) / ey;
    const float cz = (xyz[3 * i + 2] - bz0) / ez;

    const bool inside = (cx >= 0.f) && (cx <= 1.f) &&
                        (cy >= 0.f) && (cy <= 1.f) &&
                        (cz >= 0.f) && (cz <= 1.f);
    out[i] = inside ? 1.f : 0.f;

    const float x = fminf(fmaxf(cx, 0.f), 1.f);
    const float y = fminf(fmaxf(cy, 0.f), 1.f);
    const float z = fminf(fmaxf(cz, 0.f), 1.f);

    for (int c = 0; c < 8; ++c) {          // level pair (2c, 2c+1)
        unsigned idx[2][8];
        float    wt[2][8];
#pragma unroll
        for (int s = 0; s < 2; ++s) {
            const int l = 2 * c + s;
            const float scale = 16.f * (float)(1u << l);
            const float px = x * scale, py = y * scale, pz = z * scale;
            const float fx = floorf(px), fy = floorf(py), fz = floorf(pz);
            const float rx = px - fx, ry = py - fy, rz = pz - fz;
            const unsigned ux = (unsigned)fx, uy = (unsigned)fy, uz = (unsigned)fz;
            const unsigned hx[2] = { ux,        ux + 1u };
            const unsigned hy[2] = { uy * PR1, (uy + 1u) * PR1 };
            const unsigned hz[2] = { uz * PR2, (uz + 1u) * PR2 };
            const float    wx[2] = { 1.f - rx, rx };
            const float    wy[2] = { 1.f - ry, ry };
            const float    wz[2] = { 1.f - rz, rz };
#pragma unroll
            for (int cr = 0; cr < 8; ++cr) {
                const int ox = (cr >> 2) & 1, oy = (cr >> 1) & 1, oz = cr & 1;
                idx[s][cr] = ((hx[ox] ^ hy[oy] ^ hz[oz]) & (TSZ - 1u)) + (unsigned)(l * TSZ);
                wt[s][cr] = wx[ox] * wy[oy] * wz[oz];
            }
        }
        uint2 raw[16];                      // 16 independent 8B gathers in flight
#pragma unroll
        for (int k = 0; k < 16; ++k)
            raw[k] = *reinterpret_cast<const uint2*>(tbl + (size_t)idx[k >> 3][k & 7] * 4);

        float ac[2][4] = {{0.f,0.f,0.f,0.f},{0.f,0.f,0.f,0.f}};
#pragma unroll
        for (int k = 0; k < 16; ++k) {
            const int s = k >> 3;
            const float w = wt[s][k & 7];
            const unsigned d0 = raw[k].x, d1 = raw[k].y;
            ac[s][0] = fmaf(w, __builtin_bit_cast(float, d0 << 16),          ac[s][0]);
            ac[s][1] = fmaf(w, __builtin_bit_cast(float, d0 & 0xffff0000u), ac[s][1]);
            ac[s][2] = fmaf(w, __builtin_bit_cast(float, d1 << 16),          ac[s][2]);
            ac[s][3] = fmaf(w, __builtin_bit_cast(float, d1 & 0xffff0000u), ac[s][3]);
        }
        bf16x8 v;
#pragma unroll
        for (int f = 0; f < 4; ++f) {
            v[f]     = (short)f2bf(ac[0][f]);
            v[4 + f] = (short)f2bf(ac[1][f]);
        }
        // coalesced 1KB/wave nontemporal store (don't evict the table from L2)
        __builtin_nontemporal_store(v,
            reinterpret_cast<bf16x8*>(enc + ((size_t)c * Npad + i) * 8));
    }
}

// ---------------- K2: MLP via MFMA, zero barriers (wave-private tiles) ----------------
__global__ __launch_bounds__(256) void k_mlp(
    const unsigned short* __restrict__ wf, const unsigned short* __restrict__ enc,
    float* __restrict__ out, int N, int Npad)
{
    __shared__ unsigned short hT[8 * 256 * 8];  // [c][pt][8] bf16, 32KB
    __shared__ float resS[256 * 8];             // 8KB

    const int t = threadIdx.x, wv = t >> 6, ln = t & 63;
    const int col = ln & 15, g = ln >> 4;
    const int ptb = blockIdx.x * 256;
    const int i = ptb + t;

    // A0 fragments straight from global (coalesced, streaming)
    bf16x8 a0[2][4];
#pragma unroll
    for (int kk = 0; kk < 2; ++kk)
#pragma unroll
        for (int mt = 0; mt < 4; ++mt) {
            const size_t pt = (size_t)ptb + wv * 64 + mt * 16 + col;
            a0[kk][mt] = __builtin_nontemporal_load(
                reinterpret_cast<const bf16x8*>(enc + ((size_t)(kk * 4 + g) * Npad + pt) * 8));
        }
    // B0 fragments: linear, L1/L2-hot
    bf16x8 b0[4][2];
#pragma unroll
    for (int nt = 0; nt < 4; ++nt)
#pragma unroll
        for (int kk = 0; kk < 2; ++kk)
            b0[nt][kk] = *reinterpret_cast<const bf16x8*>(wf + ((nt * 2 + kk) * 64 + ln) * 8);

    f32x4 acc[4][4];
#pragma unroll
    for (int mt = 0; mt < 4; ++mt)
#pragma unroll
        for (int nt = 0; nt < 4; ++nt) acc[mt][nt] = (f32x4){0.f, 0.f, 0.f, 0.f};

#pragma unroll
    for (int kk = 0; kk < 2; ++kk)
#pragma unroll
        for (int nt = 0; nt < 4; ++nt)
#pragma unroll
            for (int mt = 0; mt < 4; ++mt)
                acc[mt][nt] = __builtin_amdgcn_mfma_f32_16x16x32_bf16(a0[kk][mt], b0[nt][kk], acc[mt][nt], 0, 0, 0);

    // relu + H0 -> hT (wave-private rows; in-wave lgkmcnt ordering suffices)
#pragma unroll
    for (int mt = 0; mt < 4; ++mt)
#pragma unroll
        for (int nt = 0; nt < 4; ++nt) {
            const int kt = nt * 2 + (col >> 3), j = col & 7;
#pragma unroll
            for (int r = 0; r < 4; ++r)
                hT[kt * 2048 + (wv * 64 + mt * 16 + g * 4 + r) * 8 + j] =
                    f2bf(fmaxf(acc[mt][nt][r], 0.f));
        }

    // ---- layer 1 ----
    bf16x8 b1[4][2];
#pragma unroll
    for (int nt = 0; nt < 4; ++nt)
#pragma unroll
        for (int kk = 0; kk < 2; ++kk)
            b1[nt][kk] = *reinterpret_cast<const bf16x8*>(wf + 4096 + ((nt * 2 + kk) * 64 + ln) * 8);

#pragma unroll
    for (int mt = 0; mt < 4; ++mt)
#pragma unroll
        for (int nt = 0; nt < 4; ++nt) acc[mt][nt] = (f32x4){0.f, 0.f, 0.f, 0.f};

#pragma unroll
    for (int kk = 0; kk < 2; ++kk) {
        bf16x8 a[4];
#pragma unroll
        for (int mt = 0; mt < 4; ++mt)
            a[mt] = *reinterpret_cast<bf16x8*>(
                &hT[(kk * 4 + g) * 2048 + (wv * 64 + mt * 16 + col) * 8]);
#pragma unroll
        for (int nt = 0; nt < 4; ++nt)
#pragma unroll
            for (int mt = 0; mt < 4; ++mt)
                acc[mt][nt] = __builtin_amdgcn_mfma_f32_16x16x32_bf16(a[mt], b1[nt][kk], acc[mt][nt], 0, 0, 0);
    }

#pragma unroll
    for (int mt = 0; mt < 4; ++mt)
#pragma unroll
        for (int nt = 0; nt < 4; ++nt) {
            const int kt = nt * 2 + (col >> 3), j = col & 7;
#pragma unroll
            for (int r = 0; r < 4; ++r)
                hT[kt * 2048 + (wv * 64 + mt * 16 + g * 4 + r) * 8 + j] =
                    f2bf(fmaxf(acc[mt][nt][r], 0.f));
        }

    // ---- layer 2 ----
    f32x4 acc2[4];
#pragma unroll
    for (int mt = 0; mt < 4; ++mt) acc2[mt] = (f32x4){0.f, 0.f, 0.f, 0.f};

#pragma unroll
    for (int kk = 0; kk < 2; ++kk) {
        const bf16x8 b2 = *reinterpret_cast<const bf16x8*>(wf + 8192 + (kk * 64 + ln) * 8);
        bf16x8 a[4];
#pragma unroll
        for (int mt = 0; mt < 4; ++mt)
            a[mt] = *reinterpret_cast<bf16x8*>(
                &hT[(kk * 4 + g) * 2048 + (wv * 64 + mt * 16 + col) * 8]);
#pragma unroll
        for (int mt = 0; mt < 4; ++mt)
            acc2[mt] = __builtin_amdgcn_mfma_f32_16x16x32_bf16(a[mt], b2, acc2[mt], 0, 0, 0);
    }

    if (col < 8) {
#pragma unroll
        for (int mt = 0; mt < 4; ++mt)
#pragma unroll
            for (int r = 0; r < 4; ++r)
                resS[(wv * 64 + mt * 16 + g * 4 + r) * 8 + col] = acc2[mt][r];
    }
    __syncthreads();

    if (i < N) {
        const bool inside = (out[i] != 0.f);    // mask written by K1
        const f32x4 lo = *reinterpret_cast<f32x4*>(&resS[t * 8 + 0]);
        const f32x4 hi = *reinterpret_cast<f32x4*>(&resS[t * 8 + 4]);

        float* __restrict__ dxyz = out + N;
        dxyz[3 * i + 0] = inside ? lo.x : 0.f;
        dxyz[3 * i + 1] = inside ? lo.y : 0.f;
        dxyz[3 * i + 2] = inside ? lo.z : 0.f;

        float4* __restrict__ drot = reinterpret_cast<float4*>(out + 4 * (size_t)N);
        drot[i] = inside ? make_float4(lo.w, hi.x, hi.y, hi.z)
                         : make_float4(1.f, 0.f, 0.f, 0.f);
    }
}

// ---------------- Fallback: round-2 fused kernel (used only if ws too small) ----------------
__global__ __launch_bounds__(256) void ntc_fused(
    const float* __restrict__ xyz, const float* __restrict__ bmin, const float* __restrict__ bmax,
    const float* __restrict__ table, const float* __restrict__ w0, const float* __restrict__ w1,
    const float* __restrict__ w2, float* __restrict__ out, int N)
{
    __shared__ unsigned short encT[8 * 256 * 8];
    __shared__ unsigned short w0t[64 * 64];
    __shared__ unsigned short w1t[64 * 64];
    __shared__ unsigned short w2t[16 * 64];

    const int t = threadIdx.x, wv = t >> 6, ln = t & 63;
    const int col = ln & 15, g = ln >> 4;

#pragma unroll
    for (int it = 0; it < 16; ++it) {
        const int idx = it * 256 + t;
        const int k = idx >> 6, n = idx & 63;
        w0t[n * 64 + k] = f2bf(w0[idx]);
        w1t[n * 64 + k] = f2bf(w1[idx]);
    }
#pragma unroll
    for (int q = 0; q < 4; ++q) {
        const int idx = t * 4 + q;
        const int n = idx >> 6, k = idx & 63;
        w2t[idx] = (n < 8) ? f2bf(w2[k * 8 + n]) : (unsigned short)0;
    }

    const int i = blockIdx.x * 256 + t;
    const int ic = (i < N) ? i : (N - 1);
    const float bx0 = bmin[0], by0 = bmin[1], bz0 = bmin[2];
    const float ex = bmax[0] - bx0, ey = bmax[1] - by0, ez = bmax[2] - bz0;
    const float cx = (xyz[3 * ic + 0] - bx0) / ex;
    const float cy = (xyz[3 * ic + 1] - by0) / ey;
    const float cz = (xyz[3 * ic + 2] - bz0) / ez;
    const bool inside = (cx >= 0.f) && (cx <= 1.f) && (cy >= 0.f) && (cy <= 1.f) &&
                        (cz >= 0.f) && (cz <= 1.f);
    const float x = fminf(fmaxf(cx, 0.f), 1.f);
    const float y = fminf(fmaxf(cy, 0.f), 1.f);
    const float z = fminf(fmaxf(cz, 0.f), 1.f);
    const float4* __restrict__ tab = reinterpret_cast<const float4*>(table);

    for (int l = 0; l < LVL; ++l) {
        const float scale = 16.f * (float)(1u << l);
        const float px = x * scale, py = y * scale, pz = z * scale;
        const float fx = floorf(px), fy = floorf(py), fz = floorf(pz);
        const float rx = px - fx, ry = py - fy, rz = pz - fz;
        const unsigned ux = (unsigned)fx, uy = (unsigned)fy, uz = (unsigned)fz;
        const unsigned hx[2] = { ux, ux + 1u };
        const unsigned hy[2] = { uy * PR1, (uy + 1u) * PR1 };
        const unsigned hz[2] = { uz * PR2, (uz + 1u) * PR2 };
        const float wx[2] = { 1.f - rx, rx };
        const float wy[2] = { 1.f - ry, ry };
        const float wz[2] = { 1.f - rz, rz };
        float a0 = 0.f, a1 = 0.f, a2 = 0.f, a3 = 0.f;
#pragma unroll
        for (int c = 0; c < 8; ++c) {
            const int ox = (c >> 2) & 1, oy = (c >> 1) & 1, oz = c & 1;
            const unsigned idx = (hx[ox] ^ hy[oy] ^ hz[oz]) & (TSZ - 1u);
            const float4 f4 = tab[l * TSZ + idx];
            const float w = wx[ox] * wy[oy] * wz[oz];
            a0 = fmaf(w, f4.x, a0); a1 = fmaf(w, f4.y, a1);
            a2 = fmaf(w, f4.z, a2); a3 = fmaf(w, f4.w, a3);
        }
        u16x4 v = { f2bf(a0), f2bf(a1), f2bf(a2), f2bf(a3) };
        *reinterpret_cast<u16x4*>(&encT[(l >> 1) * 2048 + t * 8 + (l & 1) * 4]) = v;
    }
    __syncthreads();

    f32x4 acc[4][4];
#pragma unroll
    for (int mt = 0; mt < 4; ++mt)
#pragma unroll
        for (int nt = 0; nt < 4; ++nt) acc[mt][nt] = (f32x4){0.f, 0.f, 0.f, 0.f};
#pragma unroll
    for (int kk = 0; kk < 2; ++kk) {
        bf16x8 a[4];
#pragma unroll
        for (int mt = 0; mt < 4; ++mt)
            a[mt] = *reinterpret_cast<bf16x8*>(&encT[(kk * 4 + g) * 2048 + (wv * 64 + mt * 16 + col) * 8]);
#pragma unroll
        for (int nt = 0; nt < 4; ++nt) {
            bf16x8 b = *reinterpret_cast<bf16x8*>(&w0t[(nt * 16 + col) * 64 + kk * 32 + g * 8]);
#pragma unroll
            for (int mt = 0; mt < 4; ++mt)
                acc[mt][nt] = __builtin_amdgcn_mfma_f32_16x16x32_bf16(a[mt], b, acc[mt][nt], 0, 0, 0);
        }
    }
    __syncthreads();
#pragma unroll
    for (int mt = 0; mt < 4; ++mt)
#pragma unroll
        for (int nt = 0; nt < 4; ++nt) {
            const int kt = nt * 2 + (col >> 3), j = col & 7;
#pragma unroll
            for (int r = 0; r < 4; ++r)
                encT[kt * 2048 + (wv * 64 + mt * 16 + g * 4 + r) * 8 + j] = f2bf(fmaxf(acc[mt][nt][r], 0.f));
        }
    __syncthreads();
#pragma unroll
    for (int mt = 0; mt < 4; ++mt)
#pragma unroll
        for (int nt = 0; nt < 4; ++nt) acc[mt][nt] = (f32x4){0.f, 0.f, 0.f, 0.f};
#pragma unroll
    for (int kk = 0; kk < 2; ++kk) {
        bf16x8 a[4];
#pragma unroll
        for (int mt = 0; mt < 4; ++mt)
            a[mt] = *reinterpret_cast<bf16x8*>(&encT[(kk * 4 + g) * 2048 + (wv * 64 + mt * 16 + col) * 8]);
#pragma unroll
        for (int nt = 0; nt < 4; ++nt) {
            bf16x8 b = *reinterpret_cast<bf16x8*>(&w1t[(nt * 16 + col) * 64 + kk * 32 + g * 8]);
#pragma unroll
            for (int mt = 0; mt < 4; ++mt)
                acc[mt][nt] = __builtin_amdgcn_mfma_f32_16x16x32_bf16(a[mt], b, acc[mt][nt], 0, 0, 0);
        }
    }
    __syncthreads();
#pragma unroll
    for (int mt = 0; mt < 4; ++mt)
#pragma unroll
        for (int nt = 0; nt < 4; ++nt) {
            const int kt = nt * 2 + (col >> 3), j = col & 7;
#pragma unroll
            for (int r = 0; r < 4; ++r)
                encT[kt * 2048 + (wv * 64 + mt * 16 + g * 4 + r) * 8 + j] = f2bf(fmaxf(acc[mt][nt][r], 0.f));
        }
    __syncthreads();
    f32x4 acc2[4];
#pragma unroll
    for (int mt = 0; mt < 4; ++mt) acc2[mt] = (f32x4){0.f, 0.f, 0.f, 0.f};
#pragma unroll
    for (int kk = 0; kk < 2; ++kk) {
        bf16x8 a[4];
#pragma unroll
        for (int mt = 0; mt < 4; ++mt)
            a[mt] = *reinterpret_cast<bf16x8*>(&encT[(kk * 4 + g) * 2048 + (wv * 64 + mt * 16 + col) * 8]);
        bf16x8 b = *reinterpret_cast<bf16x8*>(&w2t[col * 64 + kk * 32 + g * 8]);
#pragma unroll
        for (int mt = 0; mt < 4; ++mt)
            acc2[mt] = __builtin_amdgcn_mfma_f32_16x16x32_bf16(a[mt], b, acc2[mt], 0, 0, 0);
    }
    __syncthreads();
    float* res = reinterpret_cast<float*>(encT);
    if (col < 8) {
#pragma unroll
        for (int mt = 0; mt < 4; ++mt)
#pragma unroll
            for (int r = 0; r < 4; ++r)
                res[(wv * 64 + mt * 16 + g * 4 + r) * 8 + col] = acc2[mt][r];
    }
    __syncthreads();
    if (i < N) {
        const f32x4 lo = *reinterpret_cast<f32x4*>(&res[t * 8 + 0]);
        const f32x4 hi = *reinterpret_cast<f32x4*>(&res[t * 8 + 4]);
        out[i] = inside ? 1.f : 0.f;
        float* __restrict__ dxyz = out + N;
        dxyz[3 * i + 0] = inside ? lo.x : 0.f;
        dxyz[3 * i + 1] = inside ? lo.y : 0.f;
        dxyz[3 * i + 2] = inside ? lo.z : 0.f;
        float4* __restrict__ drot = reinterpret_cast<float4*>(out + 4 * (size_t)N);
        drot[i] = inside ? make_float4(lo.w, hi.x, hi.y, hi.z)
                         : make_float4(1.f, 0.f, 0.f, 0.f);
    }
}

extern "C" void kernel_launch(void* const* d_in, const int* in_sizes, int n_in,
                              void* d_out, int out_size, void* d_ws, size_t ws_size,
                              hipStream_t stream) {
    const float* xyz   = (const float*)d_in[0];
    const float* bmin  = (const float*)d_in[1];
    const float* bmax  = (const float*)d_in[2];
    const float* table = (const float*)d_in[3];
    const float* w0    = (const float*)d_in[4];
    const float* w1    = (const float*)d_in[5];
    const float* w2    = (const float*)d_in[6];
    float* out = (float*)d_out;

    const int N = in_sizes[0] / 3;
    const int nb = (N + 255) / 256;
    const int Npad = nb * 256;
    const int tblElems = in_sizes[3];                 // L*T*F

    size_t offW = ((size_t)tblElems * 2 + 63) & ~(size_t)63;
    size_t offEnc = (offW + 9216 * 2 + 255) & ~(size_t)255;
    size_t need = offEnc + (size_t)Npad * 128;

    if (ws_size >= need) {
        unsigned short* wsTbl = (unsigned short*)d_ws;
        unsigned short* wfr   = (unsigned short*)((char*)d_ws + offW);
        unsigned short* enc   = (unsigned short*)((char*)d_ws + offEnc);
        const int n8 = tblElems / 8;
        k_tbl<<<(n8 + 255) / 256, 256, 0, stream>>>(table, wsTbl, n8);
        k_wts<<<1, 256, 0, stream>>>(w0, w1, w2, wfr);
        k_enc<<<nb, 256, 0, stream>>>(xyz, bmin, bmax, wsTbl, out, enc, N, Npad);
        k_mlp<<<nb, 256, 0, stream>>>(wfr, enc, out, N, Npad);
    } else {
        ntc_fused<<<nb, 256, 0, stream>>>(xyz, bmin, bmax, table, w0, w1, w2, out, N);
    }
}

// Round 4
// 196.205 us; speedup vs baseline: 3.4760x; 2.6103x over previous
//
#include <hip/hip_runtime.h>
#include <hip/hip_bf16.h>

// NeuralTransformationCache, 4 kernels:
//   k_tbl8: table f32 -> fp8 e4m3 (x256 scale)   [2MB, L2-resident]
//   k_wts : weights -> MFMA-fragment bf16
//   k_enc : LDS-staged per-level gather encode (1 block/CU, 128KB LDS)
//   k_mlp : bf16 MFMA MLP (unchanged from round 3)
// Fallback fused kernel if ws too small.

#define LVL 16
#define TSZ 32768
#define PR1 2654435761u
#define PR2 805459861u

typedef __attribute__((ext_vector_type(8))) short bf16x8;
typedef __attribute__((ext_vector_type(4))) float f32x4;
typedef __attribute__((ext_vector_type(2))) float f32x2;
typedef __attribute__((ext_vector_type(4))) unsigned short u16x4;

__device__ __forceinline__ unsigned short f2bf(float f) {
    return __builtin_bit_cast(unsigned short, __float2bfloat16(f));
}

// ---- fp8 e4m3fn (OCP) encode/decode, hw builtins with sw fallback ----
__device__ __forceinline__ unsigned f32x4_to_fp8x4(float f0, float f1, float f2, float f3) {
#if __has_builtin(__builtin_amdgcn_cvt_pk_fp8_f32)
    int u = 0;
    u = __builtin_amdgcn_cvt_pk_fp8_f32(f0, f1, u, false);
    u = __builtin_amdgcn_cvt_pk_fp8_f32(f2, f3, u, true);
    return (unsigned)u;
#else
    float ff[4] = { f0, f1, f2, f3 };
    unsigned u = 0;
    for (int k = 0; k < 4; ++k) {
        const float v = ff[k];
        const unsigned s = v < 0.f ? 1u : 0u;
        float av = fabsf(v);
        unsigned b;
        if (av < 6.103515625e-05f) {          // < 2^-14: rounds to 0
            b = 0u;
        } else if (av < 0.015625f) {          // subnormal, unit 2^-9
            b = (unsigned)rintf(av * 512.f);
        } else {
            int e; float m = frexpf(av, &e);  // av = m*2^e, m in [0.5,1)
            unsigned E = (unsigned)(e - 1 + 7);
            unsigned q = (unsigned)rintf(m * 16.f);   // 8..16
            if (q == 16u) { q = 8u; ++E; }
            b = (E << 3) | (q - 8u);
        }
        u |= ((s << 7) | b) << (8 * k);
    }
    return u;
#endif
}

__device__ __forceinline__ void fp8x4_to_f32(unsigned r, float f[4]) {
#if __has_builtin(__builtin_amdgcn_cvt_pk_f32_fp8)
    const f32x2 lo = __builtin_amdgcn_cvt_pk_f32_fp8((int)r, false);
    const f32x2 hi = __builtin_amdgcn_cvt_pk_f32_fp8((int)r, true);
    f[0] = lo[0]; f[1] = lo[1]; f[2] = hi[0]; f[3] = hi[1];
#else
#pragma unroll
    for (int k = 0; k < 4; ++k) {
        const unsigned b = (r >> (8 * k)) & 0xffu;
        const unsigned s = b >> 7, em = b & 0x7fu, e = em >> 3, m = em & 7u;
        float v;
        if (e) v = __builtin_bit_cast(float, ((e + 120u) << 23) | (m << 20));
        else   v = (float)m * 0.001953125f;   // 2^-9
        f[k] = s ? -v : v;
    }
#endif
}

// ---------------- K0a: table f32 -> fp8 (x256) ----------------
__global__ __launch_bounds__(256) void k_tbl8(const float* __restrict__ t,
                                              unsigned* __restrict__ o, int n4) {
    const int g = blockIdx.x * 256 + threadIdx.x;
    if (g >= n4) return;
    const float4 a = reinterpret_cast<const float4*>(t)[g];
    o[g] = f32x4_to_fp8x4(a.x * 256.f, a.y * 256.f, a.z * 256.f, a.w * 256.f);
}

// ---------------- K0b: weights -> MFMA-fragment order, bf16 ----------------
__global__ void k_wts(const float* __restrict__ w0, const float* __restrict__ w1,
                      const float* __restrict__ w2, unsigned short* __restrict__ wf) {
    const int t = threadIdx.x;
#pragma unroll
    for (int q = 0; q < 16; ++q) {
        const int s = q * 256 + t;
        const int e = s & 7, f = s >> 3;
        const int lnn = f & 63, ntkk = f >> 6;
        const int k = (ntkk & 1) * 32 + (lnn >> 4) * 8 + e;
        const int n = (ntkk >> 1) * 16 + (lnn & 15);
        wf[s]        = f2bf(w0[k * 64 + n]);
        wf[4096 + s] = f2bf(w1[k * 64 + n]);
    }
#pragma unroll
    for (int q = 0; q < 4; ++q) {
        const int s = q * 256 + t;
        const int e = s & 7, f = s >> 3;
        const int lnn = f & 63, kk = f >> 6;
        const int k = kk * 32 + (lnn >> 4) * 8 + e;
        const int n = lnn & 15;
        wf[8192 + s] = (n < 8) ? f2bf(w2[k * 8 + n]) : (unsigned short)0;
    }
}

// ---------------- K1: LDS-staged encode ----------------
// 1024 threads/block, 4 pts/thread, 128KB LDS table slice, loop over 16 levels.
__global__ __launch_bounds__(1024) void k_enc(
    const float* __restrict__ xyz, const float* __restrict__ bmin, const float* __restrict__ bmax,
    const unsigned* __restrict__ tbl8, float* __restrict__ out,
    unsigned short* __restrict__ enc, int N, int Npad)
{
    __shared__ unsigned tabL[TSZ];     // 128KB: one level, fp8x4 per entry

    const int t = threadIdx.x;
    const int base = blockIdx.x * 4096;

    const float bx0 = bmin[0], by0 = bmin[1], bz0 = bmin[2];
    const float ex = bmax[0] - bx0, ey = bmax[1] - by0, ez = bmax[2] - bz0;

    float X[4], Y[4], Z[4];
#pragma unroll
    for (int q = 0; q < 4; ++q) {
        const int p  = base + q * 1024 + t;
        const int pc = p < N ? p : N - 1;
        const float cx = (xyz[3 * pc + 0] - bx0) / ex;
        const float cy = (xyz[3 * pc + 1] - by0) / ey;
        const float cz = (xyz[3 * pc + 2] - bz0) / ez;
        const bool inside = (cx >= 0.f) && (cx <= 1.f) && (cy >= 0.f) && (cy <= 1.f) &&
                            (cz >= 0.f) && (cz <= 1.f);
        if (p < N) out[p] = inside ? 1.f : 0.f;
        X[q] = fminf(fmaxf(cx, 0.f), 1.f);
        Y[q] = fminf(fmaxf(cy, 0.f), 1.f);
        Z[q] = fminf(fmaxf(cz, 0.f), 1.f);
    }

    for (int l = 0; l < LVL; ++l) {
        __syncthreads();               // everyone done reading previous level
        {
            const uint4* __restrict__ src = reinterpret_cast<const uint4*>(tbl8 + (size_t)l * TSZ);
            uint4* dst = reinterpret_cast<uint4*>(tabL);
#pragma unroll
            for (int j = 0; j < 8; ++j) dst[j * 1024 + t] = src[j * 1024 + t];
        }
        __syncthreads();

        const float scale = 16.f * (float)(1u << l);
#pragma unroll
        for (int q = 0; q < 4; ++q) {
            const float px = X[q] * scale, py = Y[q] * scale, pz = Z[q] * scale;
            const float fx = floorf(px), fy = floorf(py), fz = floorf(pz);
            const float rx = px - fx, ry = py - fy, rz = pz - fz;
            const unsigned ux = (unsigned)fx, uy = (unsigned)fy, uz = (unsigned)fz;
            const unsigned hx[2] = { ux, ux + 1u };
            const unsigned hy[2] = { uy * PR1, uy * PR1 + PR1 };
            const unsigned hz[2] = { uz * PR2, uz * PR2 + PR2 };
            const float    wx[2] = { 1.f - rx, rx };
            const float    wy[2] = { 1.f - ry, ry };
            // fold the fp8 x256 table scale into wz
            const float    wz[2] = { (1.f - rz) * (1.f / 256.f), rz * (1.f / 256.f) };

            unsigned r[8];
#pragma unroll
            for (int c = 0; c < 8; ++c)
                r[c] = tabL[(hx[(c >> 2) & 1] ^ hy[(c >> 1) & 1] ^ hz[c & 1]) & (TSZ - 1u)];

            float a0 = 0.f, a1 = 0.f, a2 = 0.f, a3 = 0.f;
#pragma unroll
            for (int c = 0; c < 8; ++c) {
                float f[4];
                fp8x4_to_f32(r[c], f);
                const float w = wx[(c >> 2) & 1] * wy[(c >> 1) & 1] * wz[c & 1];
                a0 = fmaf(w, f[0], a0);
                a1 = fmaf(w, f[1], a1);
                a2 = fmaf(w, f[2], a2);
                a3 = fmaf(w, f[3], a3);
            }

            const int p = base + q * 1024 + t;   // p < Npad always; dup writes benign
            u16x4 v = { f2bf(a0), f2bf(a1), f2bf(a2), f2bf(a3) };
            *reinterpret_cast<u16x4*>(enc + ((size_t)(l >> 1) * Npad + p) * 8 + (l & 1) * 4) = v;
        }
    }
}

// ---------------- K2: MLP via MFMA (unchanged from round 3) ----------------
__global__ __launch_bounds__(256) void k_mlp(
    const unsigned short* __restrict__ wf, const unsigned short* __restrict__ enc,
    float* __restrict__ out, int N, int Npad)
{
    __shared__ unsigned short hT[8 * 256 * 8];
    __shared__ float resS[256 * 8];

    const int t = threadIdx.x, wv = t >> 6, ln = t & 63;
    const int col = ln & 15, g = ln >> 4;
    const int ptb = blockIdx.x * 256;
    const int i = ptb + t;

    bf16x8 a0[2][4];
#pragma unroll
    for (int kk = 0; kk < 2; ++kk)
#pragma unroll
        for (int mt = 0; mt < 4; ++mt) {
            const size_t pt = (size_t)ptb + wv * 64 + mt * 16 + col;
            a0[kk][mt] = __builtin_nontemporal_load(
                reinterpret_cast<const bf16x8*>(enc + ((size_t)(kk * 4 + g) * Npad + pt) * 8));
        }
    bf16x8 b0[4][2];
#pragma unroll
    for (int nt = 0; nt < 4; ++nt)
#pragma unroll
        for (int kk = 0; kk < 2; ++kk)
            b0[nt][kk] = *reinterpret_cast<const bf16x8*>(wf + ((nt * 2 + kk) * 64 + ln) * 8);

    f32x4 acc[4][4];
#pragma unroll
    for (int mt = 0; mt < 4; ++mt)
#pragma unroll
        for (int nt = 0; nt < 4; ++nt) acc[mt][nt] = (f32x4){0.f, 0.f, 0.f, 0.f};

#pragma unroll
    for (int kk = 0; kk < 2; ++kk)
#pragma unroll
        for (int nt = 0; nt < 4; ++nt)
#pragma unroll
            for (int mt = 0; mt < 4; ++mt)
                acc[mt][nt] = __builtin_amdgcn_mfma_f32_16x16x32_bf16(a0[kk][mt], b0[nt][kk], acc[mt][nt], 0, 0, 0);

#pragma unroll
    for (int mt = 0; mt < 4; ++mt)
#pragma unroll
        for (int nt = 0; nt < 4; ++nt) {
            const int kt = nt * 2 + (col >> 3), j = col & 7;
#pragma unroll
            for (int r = 0; r < 4; ++r)
                hT[kt * 2048 + (wv * 64 + mt * 16 + g * 4 + r) * 8 + j] =
                    f2bf(fmaxf(acc[mt][nt][r], 0.f));
        }

    bf16x8 b1[4][2];
#pragma unroll
    for (int nt = 0; nt < 4; ++nt)
#pragma unroll
        for (int kk = 0; kk < 2; ++kk)
            b1[nt][kk] = *reinterpret_cast<const bf16x8*>(wf + 4096 + ((nt * 2 + kk) * 64 + ln) * 8);

#pragma unroll
    for (int mt = 0; mt < 4; ++mt)
#pragma unroll
        for (int nt = 0; nt < 4; ++nt) acc[mt][nt] = (f32x4){0.f, 0.f, 0.f, 0.f};

#pragma unroll
    for (int kk = 0; kk < 2; ++kk) {
        bf16x8 a[4];
#pragma unroll
        for (int mt = 0; mt < 4; ++mt)
            a[mt] = *reinterpret_cast<bf16x8*>(
                &hT[(kk * 4 + g) * 2048 + (wv * 64 + mt * 16 + col) * 8]);
#pragma unroll
        for (int nt = 0; nt < 4; ++nt)
#pragma unroll
            for (int mt = 0; mt < 4; ++mt)
                acc[mt][nt] = __builtin_amdgcn_mfma_f32_16x16x32_bf16(a[mt], b1[nt][kk], acc[mt][nt], 0, 0, 0);
    }

#pragma unroll
    for (int mt = 0; mt < 4; ++mt)
#pragma unroll
        for (int nt = 0; nt < 4; ++nt) {
            const int kt = nt * 2 + (col >> 3), j = col & 7;
#pragma unroll
            for (int r = 0; r < 4; ++r)
                hT[kt * 2048 + (wv * 64 + mt * 16 + g * 4 + r) * 8 + j] =
                    f2bf(fmaxf(acc[mt][nt][r], 0.f));
        }

    f32x4 acc2[4];
#pragma unroll
    for (int mt = 0; mt < 4; ++mt) acc2[mt] = (f32x4){0.f, 0.f, 0.f, 0.f};

#pragma unroll
    for (int kk = 0; kk < 2; ++kk) {
        const bf16x8 b2 = *reinterpret_cast<const bf16x8*>(wf + 8192 + (kk * 64 + ln) * 8);
        bf16x8 a[4];
#pragma unroll
        for (int mt = 0; mt < 4; ++mt)
            a[mt] = *reinterpret_cast<bf16x8*>(
                &hT[(kk * 4 + g) * 2048 + (wv * 64 + mt * 16 + col) * 8]);
#pragma unroll
        for (int mt = 0; mt < 4; ++mt)
            acc2[mt] = __builtin_amdgcn_mfma_f32_16x16x32_bf16(a[mt], b2, acc2[mt], 0, 0, 0);
    }

    if (col < 8) {
#pragma unroll
        for (int mt = 0; mt < 4; ++mt)
#pragma unroll
            for (int r = 0; r < 4; ++r)
                resS[(wv * 64 + mt * 16 + g * 4 + r) * 8 + col] = acc2[mt][r];
    }
    __syncthreads();

    if (i < N) {
        const bool inside = (out[i] != 0.f);
        const f32x4 lo = *reinterpret_cast<f32x4*>(&resS[t * 8 + 0]);
        const f32x4 hi = *reinterpret_cast<f32x4*>(&resS[t * 8 + 4]);

        float* __restrict__ dxyz = out + N;
        dxyz[3 * i + 0] = inside ? lo.x : 0.f;
        dxyz[3 * i + 1] = inside ? lo.y : 0.f;
        dxyz[3 * i + 2] = inside ? lo.z : 0.f;

        float4* __restrict__ drot = reinterpret_cast<float4*>(out + 4 * (size_t)N);
        drot[i] = inside ? make_float4(lo.w, hi.x, hi.y, hi.z)
                         : make_float4(1.f, 0.f, 0.f, 0.f);
    }
}

// ---------------- Fallback: fused kernel (only if ws too small) ----------------
__global__ __launch_bounds__(256) void ntc_fused(
    const float* __restrict__ xyz, const float* __restrict__ bmin, const float* __restrict__ bmax,
    const float* __restrict__ table, const float* __restrict__ w0, const float* __restrict__ w1,
    const float* __restrict__ w2, float* __restrict__ out, int N)
{
    __shared__ unsigned short encT[8 * 256 * 8];
    __shared__ unsigned short w0t[64 * 64];
    __shared__ unsigned short w1t[64 * 64];
    __shared__ unsigned short w2t[16 * 64];

    const int t = threadIdx.x, wv = t >> 6, ln = t & 63;
    const int col = ln & 15, g = ln >> 4;

#pragma unroll
    for (int it = 0; it < 16; ++it) {
        const int idx = it * 256 + t;
        const int k = idx >> 6, n = idx & 63;
        w0t[n * 64 + k] = f2bf(w0[idx]);
        w1t[n * 64 + k] = f2bf(w1[idx]);
    }
#pragma unroll
    for (int q = 0; q < 4; ++q) {
        const int idx = t * 4 + q;
        const int n = idx >> 6, k = idx & 63;
        w2t[idx] = (n < 8) ? f2bf(w2[k * 8 + n]) : (unsigned short)0;
    }

    const int i = blockIdx.x * 256 + t;
    const int ic = (i < N) ? i : (N - 1);
    const float bx0 = bmin[0], by0 = bmin[1], bz0 = bmin[2];
    const float ex = bmax[0] - bx0, ey = bmax[1] - by0, ez = bmax[2] - bz0;
    const float cx = (xyz[3 * ic + 0] - bx0) / ex;
    const float cy = (xyz[3 * ic + 1] - by0) / ey;
    const float cz = (xyz[3 * ic + 2] - bz0) / ez;
    const bool inside = (cx >= 0.f) && (cx <= 1.f) && (cy >= 0.f) && (cy <= 1.f) &&
                        (cz >= 0.f) && (cz <= 1.f);
    const float x = fminf(fmaxf(cx, 0.f), 1.f);
    const float y = fminf(fmaxf(cy, 0.f), 1.f);
    const float z = fminf(fmaxf(cz, 0.f), 1.f);
    const float4* __restrict__ tab = reinterpret_cast<const float4*>(table);

    for (int l = 0; l < LVL; ++l) {
        const float scale = 16.f * (float)(1u << l);
        const float px = x * scale, py = y * scale, pz = z * scale;
        const float fx = floorf(px), fy = floorf(py), fz = floorf(pz);
        const float rx = px - fx, ry = py - fy, rz = pz - fz;
        const unsigned ux = (unsigned)fx, uy = (unsigned)fy, uz = (unsigned)fz;
        const unsigned hx[2] = { ux, ux + 1u };
        const unsigned hy[2] = { uy * PR1, (uy + 1u) * PR1 };
        const unsigned hz[2] = { uz * PR2, (uz + 1u) * PR2 };
        const float wx[2] = { 1.f - rx, rx };
        const float wy[2] = { 1.f - ry, ry };
        const float wz[2] = { 1.f - rz, rz };
        float a0 = 0.f, a1 = 0.f, a2 = 0.f, a3 = 0.f;
#pragma unroll
        for (int c = 0; c < 8; ++c) {
            const int ox = (c >> 2) & 1, oy = (c >> 1) & 1, oz = c & 1;
            const unsigned idx = (hx[ox] ^ hy[oy] ^ hz[oz]) & (TSZ - 1u);
            const float4 f4 = tab[l * TSZ + idx];
            const float w = wx[ox] * wy[oy] * wz[oz];
            a0 = fmaf(w, f4.x, a0); a1 = fmaf(w, f4.y, a1);
            a2 = fmaf(w, f4.z, a2); a3 = fmaf(w, f4.w, a3);
        }
        u16x4 v = { f2bf(a0), f2bf(a1), f2bf(a2), f2bf(a3) };
        *reinterpret_cast<u16x4*>(&encT[(l >> 1) * 2048 + t * 8 + (l & 1) * 4]) = v;
    }
    __syncthreads();

    f32x4 acc[4][4];
#pragma unroll
    for (int mt = 0; mt < 4; ++mt)
#pragma unroll
        for (int nt = 0; nt < 4; ++nt) acc[mt][nt] = (f32x4){0.f, 0.f, 0.f, 0.f};
#pragma unroll
    for (int kk = 0; kk < 2; ++kk) {
        bf16x8 a[4];
#pragma unroll
        for (int mt = 0; mt < 4; ++mt)
            a[mt] = *reinterpret_cast<bf16x8*>(&encT[(kk * 4 + g) * 2048 + (wv * 64 + mt * 16 + col) * 8]);
#pragma unroll
        for (int nt = 0; nt < 4; ++nt) {
            bf16x8 b = *reinterpret_cast<bf16x8*>(&w0t[(nt * 16 + col) * 64 + kk * 32 + g * 8]);
#pragma unroll
            for (int mt = 0; mt < 4; ++mt)
                acc[mt][nt] = __builtin_amdgcn_mfma_f32_16x16x32_bf16(a[mt], b, acc[mt][nt], 0, 0, 0);
        }
    }
    __syncthreads();
#pragma unroll
    for (int mt = 0; mt < 4; ++mt)
#pragma unroll
        for (int nt = 0; nt < 4; ++nt) {
            const int kt = nt * 2 + (col >> 3), j = col & 7;
#pragma unroll
            for (int r = 0; r < 4; ++r)
                encT[kt * 2048 + (wv * 64 + mt * 16 + g * 4 + r) * 8 + j] = f2bf(fmaxf(acc[mt][nt][r], 0.f));
        }
    __syncthreads();
#pragma unroll
    for (int mt = 0; mt < 4; ++mt)
#pragma unroll
        for (int nt = 0; nt < 4; ++nt) acc[mt][nt] = (f32x4){0.f, 0.f, 0.f, 0.f};
#pragma unroll
    for (int kk = 0; kk < 2; ++kk) {
        bf16x8 a[4];
#pragma unroll
        for (int mt = 0; mt < 4; ++mt)
            a[mt] = *reinterpret_cast<bf16x8*>(&encT[(kk * 4 + g) * 2048 + (wv * 64 + mt * 16 + col) * 8]);
#pragma unroll
        for (int nt = 0; nt < 4; ++nt) {
            bf16x8 b = *reinterpret_cast<bf16x8*>(&w1t[(nt * 16 + col) * 64 + kk * 32 + g * 8]);
#pragma unroll
            for (int mt = 0; mt < 4; ++mt)
                acc[mt][nt] = __builtin_amdgcn_mfma_f32_16x16x32_bf16(a[mt], b, acc[mt][nt], 0, 0, 0);
        }
    }
    __syncthreads();
#pragma unroll
    for (int mt = 0; mt < 4; ++mt)
#pragma unroll
        for (int nt = 0; nt < 4; ++nt) {
            const int kt = nt * 2 + (col >> 3), j = col & 7;
#pragma unroll
            for (int r = 0; r < 4; ++r)
                encT[kt * 2048 + (wv * 64 + mt * 16 + g * 4 + r) * 8 + j] = f2bf(fmaxf(acc[mt][nt][r], 0.f));
        }
    __syncthreads();
    f32x4 acc2[4];
#pragma unroll
    for (int mt = 0; mt < 4; ++mt) acc2[mt] = (f32x4){0.f, 0.f, 0.f, 0.f};
#pragma unroll
    for (int kk = 0; kk < 2; ++kk) {
        bf16x8 a[4];
#pragma unroll
        for (int mt = 0; mt < 4; ++mt)
            a[mt] = *reinterpret_cast<bf16x8*>(&encT[(kk * 4 + g) * 2048 + (wv * 64 + mt * 16 + col) * 8]);
        bf16x8 b = *reinterpret_cast<bf16x8*>(&w2t[col * 64 + kk * 32 + g * 8]);
#pragma unroll
        for (int mt = 0; mt < 4; ++mt)
            acc2[mt] = __builtin_amdgcn_mfma_f32_16x16x32_bf16(a[mt], b, acc2[mt], 0, 0, 0);
    }
    __syncthreads();
    float* res = reinterpret_cast<float*>(encT);
    if (col < 8) {
#pragma unroll
        for (int mt = 0; mt < 4; ++mt)
#pragma unroll
            for (int r = 0; r < 4; ++r)
                res[(wv * 64 + mt * 16 + g * 4 + r) * 8 + col] = acc2[mt][r];
    }
    __syncthreads();
    if (i < N) {
        const f32x4 lo = *reinterpret_cast<f32x4*>(&res[t * 8 + 0]);
        const f32x4 hi = *reinterpret_cast<f32x4*>(&res[t * 8 + 4]);
        out[i] = inside ? 1.f : 0.f;
        float* __restrict__ dxyz = out + N;
        dxyz[3 * i + 0] = inside ? lo.x : 0.f;
        dxyz[3 * i + 1] = inside ? lo.y : 0.f;
        dxyz[3 * i + 2] = inside ? lo.z : 0.f;
        float4* __restrict__ drot = reinterpret_cast<float4*>(out + 4 * (size_t)N);
        drot[i] = inside ? make_float4(lo.w, hi.x, hi.y, hi.z)
                         : make_float4(1.f, 0.f, 0.f, 0.f);
    }
}

extern "C" void kernel_launch(void* const* d_in, const int* in_sizes, int n_in,
                              void* d_out, int out_size, void* d_ws, size_t ws_size,
                              hipStream_t stream) {
    const float* xyz   = (const float*)d_in[0];
    const float* bmin  = (const float*)d_in[1];
    const float* bmax  = (const float*)d_in[2];
    const float* table = (const float*)d_in[3];
    const float* w0    = (const float*)d_in[4];
    const float* w1    = (const float*)d_in[5];
    const float* w2    = (const float*)d_in[6];
    float* out = (float*)d_out;

    const int N = in_sizes[0] / 3;
    const int nb = (N + 255) / 256;            // k_mlp blocks
    const int nbE = (N + 4095) / 4096;         // k_enc blocks (4096 pts each)
    const int Npad = nbE * 4096;
    const int tblElems = in_sizes[3];          // L*T*F = 2M

    size_t offW = ((size_t)tblElems + 63) & ~(size_t)63;          // fp8 table bytes
    size_t offEnc = (offW + 9216 * 2 + 255) & ~(size_t)255;
    size_t need = offEnc + (size_t)Npad * 128;

    if (ws_size >= need) {
        unsigned* tbl8      = (unsigned*)d_ws;
        unsigned short* wfr = (unsigned short*)((char*)d_ws + offW);
        unsigned short* enc = (unsigned short*)((char*)d_ws + offEnc);
        const int n4 = tblElems / 4;
        k_tbl8<<<(n4 + 255) / 256, 256, 0, stream>>>(table, tbl8, n4);
        k_wts<<<1, 256, 0, stream>>>(w0, w1, w2, wfr);
        k_enc<<<nbE, 1024, 0, stream>>>(xyz, bmin, bmax, tbl8, out, enc, N, Npad);
        k_mlp<<<nb, 256, 0, stream>>>(wfr, enc, out, N, Npad);
    } else {
        ntc_fused<<<nb, 256, 0, stream>>>(xyz, bmin, bmax, table, w0, w1, w2, out, N);
    }
}